// Round 10
// baseline (189.532 us; speedup 1.0000x reference)
//
#include <hip/hip_runtime.h>

#define PI_D 3.141592653589793238462643383279502884

// x (8,256,256,64) f32 -> out (8,256,256,64) f32.
// Forward padded FFT (272,272,80) pad=8; x_ft = Re(F)-Im(F) on 4 corner blocks.
// Inverse (256,256,64); out = Re(G)-Im(G).
// Re-Im collapse: Re-Im(sum a*w) = sum a.x*P + a.y*Qm, P=c-s, Qm=-(c+s).

// ---------------- twiddle tables (double-precision build) ----------------
__global__ void k_tables(float2* __restrict__ wt, float2* __restrict__ vt,
                         float2* __restrict__ vxy,
                         float2* __restrict__ pqf, float2* __restrict__ pqi,
                         float2* __restrict__ t16, float2* __restrict__ t1) {
  int t = blockIdx.x * blockDim.x + threadIdx.x;
  if (t < 64 * 16) {  // wt[n3][k3] = exp(-2pi i k3 (n3+8)/80)
    int n3 = t >> 4, k3 = t & 15;
    int ph = (k3 * (n3 + 8)) % 80;
    double a = -2.0 * PI_D * (double)ph / 80.0;
    wt[t] = make_float2((float)cos(a), (float)sin(a));
  }
  if (t < 256 * 32) {  // pqf[n][k]: P,Qm of exp(-2pi i kk (n+8)/272), kk = k<16?k:240+k
    int n = t >> 5, k = t & 31;
    int kk = (k < 16) ? k : (240 + k);
    int ph = (kk * (n + 8)) % 272;
    double a = -2.0 * PI_D * (double)ph / 272.0;
    double c = cos(a), s = sin(a);
    pqf[t] = make_float2((float)(c - s), (float)(-(c + s)));
  }
  if (t < 512) {  // Y-twiddle factor tables: w(n2,k2) = t16[n2>>4][k2]*t1[n2&15][k2]
    int a = t >> 5, k = t & 31;
    int kk = (k < 16) ? k : (240 + k);
    int ph16 = (kk * 16 * a) % 272;
    double a16 = -2.0 * PI_D * (double)ph16 / 272.0;
    t16[t] = make_float2((float)cos(a16), (float)sin(a16));
    int ph1 = (kk * (a + 8)) % 272;  // C0 = exp(-2pi i kk*8/272) folded in
    double a1 = -2.0 * PI_D * (double)ph1 / 272.0;
    t1[t] = make_float2((float)cos(a1), (float)sin(a1));
  }
  if (t < 16 * 64) {  // vt[k3][n3] = exp(+2pi i k3 n3 / 64)
    int k3 = t >> 6, n3 = t & 63;
    int ph = (k3 * n3) & 63;
    double a = 2.0 * PI_D * (double)ph / 64.0;
    vt[t] = make_float2((float)cos(a), (float)sin(a));
  }
  if (t < 256 * 32) {  // vxy[n][k] = exp(+2pi i k n / 256); pqi scaled by 1/N
    int n = t >> 5, k = t & 31;
    int ph = (k * n) & 255;
    double a = 2.0 * PI_D * (double)ph / 256.0;
    double c = cos(a), s = sin(a);
    vxy[t] = make_float2((float)c, (float)s);
    const double inv = 1.0 / 4194304.0;  // 1/(256*256*64)
    pqi[t] = make_float2((float)((c - s) * inv), (float)((-(c + s)) * inv));
  }
}

// ---------------- Fused forward T+Y DFT ----------------
// Per block (b,n1):  At[n2,k3] = sum_n3 x[b,n1,n2,n3]*wt[n3][k3]
//                    Bm[b,n1,k2,k3] = sum_n2 At[n2,k3]*w(n2,k2)
// __launch_bounds__(512,4): LDS caps at 2 blocks/CU (4 waves/SIMD) anyway;
// declaring it doubles the VGPR budget to 128 so unrolled ds_reads can be
// pipelined (VGPR=64 was strangling ILP -> latency-bound at 45% VALU).
__global__ __launch_bounds__(512, 4) void k_fwd(const float* __restrict__ x,
                                                float2* __restrict__ Bm,
                                                const float2* __restrict__ wtf,
                                                const float2* __restrict__ t16,
                                                const float2* __restrict__ t1) {
  __shared__ float sX[32][260];   // [n3 local][n2 xor-swizzled], 33.3 KB
  __shared__ float sAt[256][36];  // [n2][k3 re/im interleaved], 36.9 KB
  __shared__ float2 swt[1024];    // wt[64][16], 8 KB  (total 78 KB -> 2 blocks/CU)
  int bn1 = blockIdx.x;
  int tid = threadIdx.x;
  int lane = tid & 63;
  int wv = __builtin_amdgcn_readfirstlane(tid >> 6);
  int q = wv & 3, hf = wv >> 2;
  int n2a = hf * 128 + 2 * lane;
  const float4* xg = (const float4*)(x + (long)bn1 * 16384);
  // stage wt (once; covered by the first h3 barrier)
  swt[tid] = wtf[tid];
  swt[tid + 512] = wtf[tid + 512];
  float2 acc[2][4];
#pragma unroll
  for (int i = 0; i < 2; i++)
#pragma unroll
    for (int k = 0; k < 4; k++) acc[i][k] = make_float2(0.f, 0.f);
  // ---- T-phase over two n3 halves ----
  for (int h3 = 0; h3 < 2; h3++) {
    if (h3) __syncthreads();  // all reads of previous half done
#pragma unroll
    for (int e = 0; e < 4; e++) {
      int g = tid + e * 512;  // 2048 float4: n2 x 8 local quads
      int n2 = g >> 3, q3 = g & 7;
      float4 v = xg[n2 * 16 + h3 * 8 + q3];
      int cs = n2 ^ (q3 * 4);  // write-conflict-killing swizzle
      sX[4 * q3 + 0][cs] = v.x; sX[4 * q3 + 1][cs] = v.y;
      sX[4 * q3 + 2][cs] = v.z; sX[4 * q3 + 3][cs] = v.w;
    }
    __syncthreads();
#pragma unroll 4
    for (int n3l = 0; n3l < 32; n3l++) {
      float2 xv = *(const float2*)&sX[n3l][n2a ^ ((n3l >> 2) * 4)];
      const float* wr = (const float*)&swt[(h3 * 32 + n3l) * 16 + 4 * q];
      float4 wA = *(const float4*)(wr);      // broadcast b128
      float4 wB = *(const float4*)(wr + 4);  // broadcast b128
      acc[0][0].x = fmaf(xv.x, wA.x, acc[0][0].x); acc[0][0].y = fmaf(xv.x, wA.y, acc[0][0].y);
      acc[0][1].x = fmaf(xv.x, wA.z, acc[0][1].x); acc[0][1].y = fmaf(xv.x, wA.w, acc[0][1].y);
      acc[0][2].x = fmaf(xv.x, wB.x, acc[0][2].x); acc[0][2].y = fmaf(xv.x, wB.y, acc[0][2].y);
      acc[0][3].x = fmaf(xv.x, wB.z, acc[0][3].x); acc[0][3].y = fmaf(xv.x, wB.w, acc[0][3].y);
      acc[1][0].x = fmaf(xv.y, wA.x, acc[1][0].x); acc[1][0].y = fmaf(xv.y, wA.y, acc[1][0].y);
      acc[1][1].x = fmaf(xv.y, wA.z, acc[1][1].x); acc[1][1].y = fmaf(xv.y, wA.w, acc[1][1].y);
      acc[1][2].x = fmaf(xv.y, wB.x, acc[1][2].x); acc[1][2].y = fmaf(xv.y, wB.y, acc[1][2].y);
      acc[1][3].x = fmaf(xv.y, wB.z, acc[1][3].x); acc[1][3].y = fmaf(xv.y, wB.w, acc[1][3].y);
    }
  }
#pragma unroll
  for (int i = 0; i < 2; i++) {
    int row = n2a + i;
    *(float4*)&sAt[row][8 * q] =
        make_float4(acc[i][0].x, acc[i][0].y, acc[i][1].x, acc[i][1].y);
    *(float4*)&sAt[row][8 * q + 4] =
        make_float4(acc[i][2].x, acc[i][2].y, acc[i][3].x, acc[i][3].y);
  }
  // ---- Y twiddle registers (static-index tables; loads overlap barrier) ----
  int k2 = lane & 31, s = lane >> 5;
  float2 W16[16], W1s[8];
#pragma unroll
  for (int a = 0; a < 16; a++) W16[a] = t16[a * 32 + k2];
#pragma unroll
  for (int u = 0; u < 8; u++) W1s[u] = t1[(2 * u + s) * 32 + k2];
  __syncthreads();
  // ---- Y-phase (all register-array indices compile-time) ----
  {
    int p = wv;  // k3 pair
    float2 a0 = make_float2(0.f, 0.f), a1 = make_float2(0.f, 0.f);
#pragma unroll
    for (int a = 0; a < 16; a++) {
      float2 wa = W16[a];
#pragma unroll
      for (int u = 0; u < 8; u++) {
        int n2 = 16 * a + 2 * u + s;
        float4 av = *(const float4*)&sAt[n2][4 * p];  // broadcast b128
        float2 wb = W1s[u];
        float wx = fmaf(wa.x, wb.x, -wa.y * wb.y);
        float wy = fmaf(wa.x, wb.y, wa.y * wb.x);
        a0.x = fmaf(av.x, wx, fmaf(-av.y, wy, a0.x));
        a0.y = fmaf(av.x, wy, fmaf(av.y, wx, a0.y));
        a1.x = fmaf(av.z, wx, fmaf(-av.w, wy, a1.x));
        a1.y = fmaf(av.z, wy, fmaf(av.w, wx, a1.y));
      }
    }
    a0.x += __shfl_xor(a0.x, 32); a0.y += __shfl_xor(a0.y, 32);
    a1.x += __shfl_xor(a1.x, 32); a1.y += __shfl_xor(a1.y, 32);
    if (s == 0) {
      *(float4*)&Bm[(long)bn1 * 512 + k2 * 16 + 2 * p] =
          make_float4(a0.x, a0.y, a1.x, a1.y);
    }
  }
}

// ---------------- Step C: X-axis forward DFT (all-LDS, Re-Im collapsed) ----------------
__global__ __launch_bounds__(512, 2) void k_fft_x(
    const float2* __restrict__ Bm, float* __restrict__ y,
    const float2* __restrict__ pqf,
    const float* __restrict__ w_tl, const float* __restrict__ w_tr,
    const float* __restrict__ w_bl, const float* __restrict__ w_br,
    const float* __restrict__ b_tl, const float* __restrict__ b_tr,
    const float* __restrict__ b_bl, const float* __restrict__ b_br) {
  __shared__ float2 sB[4096];   // [n1][k3] 32 KB
  __shared__ float2 sPQ[8192];  // full pqf table, 64 KB
  int b = blockIdx.x >> 5, k2 = blockIdx.x & 31;
  int tid = threadIdx.x;
  for (int i = tid; i < 4096; i += 512) {
    sB[i] = Bm[((long)(b * 256 + (i >> 4)) * 32 + k2) * 16 + (i & 15)];
  }
  const float4* pq4 = (const float4*)pqf;
  float4* sPQ4 = (float4*)sPQ;
#pragma unroll
  for (int e = 0; e < 8; e++) sPQ4[tid + e * 512] = pq4[tid + e * 512];
  __syncthreads();
  int k1 = tid >> 4, k3 = tid & 15;
  float acc = 0.f;
#pragma unroll 8
  for (int n1 = 0; n1 < 256; n1++) {
    float2 a = sB[n1 * 16 + k3];
    float2 w = sPQ[n1 * 32 + k1];  // (P, Qm)
    acc = fmaf(a.x, w.x, acc);
    acc = fmaf(a.y, w.y, acc);
  }
  const float* wsel = (k1 < 16) ? ((k2 < 16) ? w_tl : w_bl) : ((k2 < 16) ? w_tr : w_br);
  const float* bsel = (k1 < 16) ? ((k2 < 16) ? b_tl : b_bl) : ((k2 < 16) ? b_tr : b_br);
  int idx = ((k1 & 15) * 16 + (k2 & 15)) * 16 + k3;
  y[((b * 32 + k1) * 32 + k2) * 16 + k3] = fmaf(acc, wsel[idx], bsel[idx]);
}

// ---------------- Steps D+E fused: T-axis then Y-axis inverse DFT (GEMM form) ----------------
__global__ __launch_bounds__(256, 2) void k_inv_te(const float* __restrict__ y,
                                                   float2* __restrict__ E,
                                                   const float2* __restrict__ vt,
                                                   const float2* __restrict__ vxy) {
  __shared__ float sy[512];      // y[b,k1,:,:]  32x16
  __shared__ float2 svt[1024];   // vt[16][64]
  __shared__ float sD[32][132];  // D re/im interleaved: [k2][2*n3], pad
  __shared__ float sV[128][66];  // V c/s interleaved: [n2 local][2*k2], pad
  int blk = blockIdx.x;          // bk1*2 + h
  int h = blk & 1, bk1 = blk >> 1;
  int tid = threadIdx.x;
  ((float2*)sy)[tid] = ((const float2*)(y + (long)bk1 * 512))[tid];
#pragma unroll
  for (int e = 0; e < 4; e++) svt[tid + e * 256] = vt[tid + e * 256];
#pragma unroll
  for (int e = 0; e < 16; e++) {  // stage V panel: 128 rows x 32 k2
    int q = tid + e * 256;
    int n2l = q >> 5, k2 = q & 31;
    float2 v = vxy[(h * 128 + n2l) * 32 + k2];
    *(float2*)&sV[n2l][2 * k2] = v;
  }
  __syncthreads();
#pragma unroll
  for (int e = 0; e < 8; e++) {  // compute D (32x64 complex)
    int idx = tid + e * 256;
    int k2 = idx >> 6, n3i = idx & 63;
    float ax = 0.f, ay = 0.f;
#pragma unroll
    for (int k3 = 0; k3 < 16; k3++) {
      float yv = sy[k2 * 16 + k3];
      float2 v = svt[k3 * 64 + n3i];
      ax = fmaf(yv, v.x, ax); ay = fmaf(yv, v.y, ay);
    }
    *(float2*)&sD[k2][2 * n3i] = make_float2(ax, ay);
  }
  __syncthreads();
  int rg = tid >> 3, tn = tid & 7;  // rows n2l = rg*4+i; cols n3 = tn*8+j
  float acc[4][16];
#pragma unroll
  for (int i = 0; i < 4; i++)
#pragma unroll
    for (int j = 0; j < 16; j++) acc[i][j] = 0.f;
#pragma unroll 2
  for (int k2 = 0; k2 < 32; k2++) {
    float4 d0 = *(const float4*)&sD[k2][tn * 16];
    float4 d1 = *(const float4*)&sD[k2][tn * 16 + 4];
    float4 d2 = *(const float4*)&sD[k2][tn * 16 + 8];
    float4 d3 = *(const float4*)&sD[k2][tn * 16 + 12];
#pragma unroll
    for (int i = 0; i < 4; i++) {
      float2 v = *(const float2*)&sV[rg * 4 + i][2 * k2];
      float c = v.x, s = v.y;
      acc[i][0]  = fmaf(c, d0.x, fmaf(-s, d0.y, acc[i][0]));
      acc[i][1]  = fmaf(c, d0.y, fmaf( s, d0.x, acc[i][1]));
      acc[i][2]  = fmaf(c, d0.z, fmaf(-s, d0.w, acc[i][2]));
      acc[i][3]  = fmaf(c, d0.w, fmaf( s, d0.z, acc[i][3]));
      acc[i][4]  = fmaf(c, d1.x, fmaf(-s, d1.y, acc[i][4]));
      acc[i][5]  = fmaf(c, d1.y, fmaf( s, d1.x, acc[i][5]));
      acc[i][6]  = fmaf(c, d1.z, fmaf(-s, d1.w, acc[i][6]));
      acc[i][7]  = fmaf(c, d1.w, fmaf( s, d1.z, acc[i][7]));
      acc[i][8]  = fmaf(c, d2.x, fmaf(-s, d2.y, acc[i][8]));
      acc[i][9]  = fmaf(c, d2.y, fmaf( s, d2.x, acc[i][9]));
      acc[i][10] = fmaf(c, d2.z, fmaf(-s, d2.w, acc[i][10]));
      acc[i][11] = fmaf(c, d2.w, fmaf( s, d2.z, acc[i][11]));
      acc[i][12] = fmaf(c, d3.x, fmaf(-s, d3.y, acc[i][12]));
      acc[i][13] = fmaf(c, d3.y, fmaf( s, d3.x, acc[i][13]));
      acc[i][14] = fmaf(c, d3.z, fmaf(-s, d3.w, acc[i][14]));
      acc[i][15] = fmaf(c, d3.w, fmaf( s, d3.z, acc[i][15]));
    }
  }
#pragma unroll
  for (int i = 0; i < 4; i++) {
    int n2g = h * 128 + rg * 4 + i;
    float4* dst = (float4*)&E[((long)bk1 * 256 + n2g) * 64 + tn * 8];
    dst[0] = make_float4(acc[i][0], acc[i][1], acc[i][2], acc[i][3]);
    dst[1] = make_float4(acc[i][4], acc[i][5], acc[i][6], acc[i][7]);
    dst[2] = make_float4(acc[i][8], acc[i][9], acc[i][10], acc[i][11]);
    dst[3] = make_float4(acc[i][12], acc[i][13], acc[i][14], acc[i][15]);
  }
}

// ---------------- Step F: X-axis inverse DFT as full-column GEMM ----------------
__global__ __launch_bounds__(256, 2) void k_ifft_x(const float2* __restrict__ E,
                                                   float* __restrict__ out,
                                                   const float2* __restrict__ pqi) {
  __shared__ float sW[64][256];  // [kk][n1] 64 KB
  __shared__ float sD[64][64];   // [kk][col] 16 KB
  int blk = blockIdx.x;          // b*256 + tc
  int tc = blk & 255, b = blk >> 8;
  int tid = threadIdx.x;
  {
    const float4* pq4 = (const float4*)pqi;
#pragma unroll
    for (int r = 0; r < 16; r++) {
      float4 v = pq4[tid * 16 + r];
      sW[4 * r][tid] = v.x; sW[4 * r + 1][tid] = v.y;
      sW[4 * r + 2][tid] = v.z; sW[4 * r + 3][tid] = v.w;
    }
  }
  {
    const float4* Eg = (const float4*)E;
#pragma unroll
    for (int e = 0; e < 2; e++) {
      int tq = tid + e * 256;
      int k1 = tq >> 4, cq = tq & 15;
      const float4* src = Eg + ((long)(b * 32 + k1) * 8192) + tc * 32 + 2 * cq;
      float4 v0 = src[0], v1 = src[1];
      *(float4*)&sD[2 * k1][4 * cq]     = make_float4(v0.x, v0.z, v1.x, v1.z);
      *(float4*)&sD[2 * k1 + 1][4 * cq] = make_float4(v0.y, v0.w, v1.y, v1.w);
    }
  }
  __syncthreads();
  int tm = tid >> 3, tn = tid & 7;
  float acc[8][8];
#pragma unroll
  for (int i = 0; i < 8; i++)
#pragma unroll
    for (int j = 0; j < 8; j++) acc[i][j] = 0.f;
#pragma unroll 2
  for (int kk = 0; kk < 64; kk++) {
    float4 wa = *(const float4*)&sW[kk][tm * 8];
    float4 wb = *(const float4*)&sW[kk][tm * 8 + 4];
    float4 da = *(const float4*)&sD[kk][tn * 8];
    float4 db = *(const float4*)&sD[kk][tn * 8 + 4];
    float w[8] = {wa.x, wa.y, wa.z, wa.w, wb.x, wb.y, wb.z, wb.w};
    float d[8] = {da.x, da.y, da.z, da.w, db.x, db.y, db.z, db.w};
#pragma unroll
    for (int i = 0; i < 8; i++)
#pragma unroll
      for (int j = 0; j < 8; j++) acc[i][j] = fmaf(w[i], d[j], acc[i][j]);
  }
  float* ob = out + (long)b * 4194304 + (long)(tm * 8) * 16384 + tc * 64 + tn * 8;
#pragma unroll
  for (int i = 0; i < 8; i++) {
    float4* o = (float4*)(ob + (long)i * 16384);
    o[0] = make_float4(acc[i][0], acc[i][1], acc[i][2], acc[i][3]);
    o[1] = make_float4(acc[i][4], acc[i][5], acc[i][6], acc[i][7]);
  }
}

extern "C" void kernel_launch(void* const* d_in, const int* in_sizes, int n_in,
                              void* d_out, int out_size, void* d_ws, size_t ws_size,
                              hipStream_t stream) {
  const float* x    = (const float*)d_in[0];
  const float* w_tl = (const float*)d_in[1];
  const float* w_tr = (const float*)d_in[2];
  const float* w_bl = (const float*)d_in[3];
  const float* w_br = (const float*)d_in[4];
  const float* b_tl = (const float*)d_in[5];
  const float* b_tr = (const float*)d_in[6];
  const float* b_bl = (const float*)d_in[7];
  const float* b_br = (const float*)d_in[8];
  float* out = (float*)d_out;
  char* ws = (char*)d_ws;

  // Workspace layout (bytes):
  float2* Bm  = (float2*)(ws + 0);          //  8,388,608  (8,256,32,16) c64
  float*  y   = (float*)(ws + 8388608);     //  2,097,152  (8,32,32,16)  f32
  float2* E   = (float2*)(ws + 10485760);   // 33,554,432  (8,32,256,64) c64
  float2* WT  = (float2*)(ws + 44040192);   //  8 KB
  float2* VT  = (float2*)(ws + 44048384);   //  8 KB
  float2* VXY = (float2*)(ws + 44056576);   // 64 KB
  float2* PQF = (float2*)(ws + 44122112);   // 64 KB
  float2* PQI = (float2*)(ws + 44187648);   // 64 KB
  float2* T16 = (float2*)(ws + 44253184);   //  4 KB
  float2* T1  = (float2*)(ws + 44257280);   //  4 KB  (end ~44.3 MB)

  k_tables<<<32, 256, 0, stream>>>(WT, VT, VXY, PQF, PQI, T16, T1);
  k_fwd<<<2048, 512, 0, stream>>>(x, Bm, WT, T16, T1);
  k_fft_x<<<256, 512, 0, stream>>>(Bm, y, PQF, w_tl, w_tr, w_bl, w_br,
                                   b_tl, b_tr, b_bl, b_br);
  k_inv_te<<<512, 256, 0, stream>>>(y, E, VT, VXY);
  k_ifft_x<<<2048, 256, 0, stream>>>(E, out, PQI);
}

// Round 11
// 186.390 us; speedup vs baseline: 1.0169x; 1.0169x over previous
//
#include <hip/hip_runtime.h>

#define PI_D 3.141592653589793238462643383279502884

// x (8,256,256,64) f32 -> out (8,256,256,64) f32.
// Forward padded FFT (272,272,80) pad=8; x_ft = Re(F)-Im(F) on 4 corner blocks.
// Inverse (256,256,64); out = Re(G)-Im(G).
// Re-Im collapse: Re-Im(sum a*w) = sum a.x*P + a.y*Qm, P=c-s, Qm=-(c+s).

// ---------------- twiddle tables (double-precision build) ----------------
__global__ void k_tables(float2* __restrict__ wt, float2* __restrict__ vt,
                         float2* __restrict__ vxy,
                         float2* __restrict__ pqf, float2* __restrict__ pqi,
                         float2* __restrict__ t16, float2* __restrict__ t1) {
  int t = blockIdx.x * blockDim.x + threadIdx.x;
  if (t < 64 * 16) {  // wt[n3][k3] = exp(-2pi i k3 (n3+8)/80)
    int n3 = t >> 4, k3 = t & 15;
    int ph = (k3 * (n3 + 8)) % 80;
    double a = -2.0 * PI_D * (double)ph / 80.0;
    wt[t] = make_float2((float)cos(a), (float)sin(a));
  }
  if (t < 256 * 32) {  // pqf[n][k]: P,Qm of exp(-2pi i kk (n+8)/272), kk = k<16?k:240+k
    int n = t >> 5, k = t & 31;
    int kk = (k < 16) ? k : (240 + k);
    int ph = (kk * (n + 8)) % 272;
    double a = -2.0 * PI_D * (double)ph / 272.0;
    double c = cos(a), s = sin(a);
    pqf[t] = make_float2((float)(c - s), (float)(-(c + s)));
  }
  if (t < 512) {  // Y-twiddle factor tables: w(n2,k2) = t16[n2>>4][k2]*t1[n2&15][k2]
    int a = t >> 5, k = t & 31;
    int kk = (k < 16) ? k : (240 + k);
    int ph16 = (kk * 16 * a) % 272;
    double a16 = -2.0 * PI_D * (double)ph16 / 272.0;
    t16[t] = make_float2((float)cos(a16), (float)sin(a16));
    int ph1 = (kk * (a + 8)) % 272;  // C0 = exp(-2pi i kk*8/272) folded in
    double a1 = -2.0 * PI_D * (double)ph1 / 272.0;
    t1[t] = make_float2((float)cos(a1), (float)sin(a1));
  }
  if (t < 16 * 64) {  // vt[k3][n3] = exp(+2pi i k3 n3 / 64)
    int k3 = t >> 6, n3 = t & 63;
    int ph = (k3 * n3) & 63;
    double a = 2.0 * PI_D * (double)ph / 64.0;
    vt[t] = make_float2((float)cos(a), (float)sin(a));
  }
  if (t < 256 * 32) {  // vxy[n][k] = exp(+2pi i k n / 256); pqi scaled by 1/N
    int n = t >> 5, k = t & 31;
    int ph = (k * n) & 255;
    double a = 2.0 * PI_D * (double)ph / 256.0;
    double c = cos(a), s = sin(a);
    vxy[t] = make_float2((float)c, (float)s);
    const double inv = 1.0 / 4194304.0;  // 1/(256*256*64)
    pqi[t] = make_float2((float)((c - s) * inv), (float)((-(c + s)) * inv));
  }
}

// ---------------- Fused forward T+Y DFT ----------------
// Per block (b,n1):  At[n2,k3] = sum_n3 x[b,n1,n2,n3]*wt[n3][k3]
//                    Bm[b,n1,k2,k3] = sum_n2 At[n2,k3]*w(n2,k2)
// T-phase: wave = k3-PAIR p (matches Y mapping); lane owns n2 = 4*lane..+3.
// Per n3-iter: 1 ds_read_b128 + 1 wave-uniform s_load_dwordx4 -> 16 FMA/LDS-op.
// x staged in QUARTERS (16 n3): LDS 53.5 KB -> 3 blocks/CU (24 waves).
__global__ __launch_bounds__(512, 6) void k_fwd(const float* __restrict__ x,
                                                float2* __restrict__ Bm,
                                                const float* __restrict__ wtf,
                                                const float2* __restrict__ t16,
                                                const float2* __restrict__ t1) {
  __shared__ float sX[16][260];   // [n3 local][n2 xor-swizzled], 16.6 KB
  __shared__ float sAt[256][36];  // [n2][k3 re/im interleaved], 36.9 KB
  int bn1 = blockIdx.x;
  int tid = threadIdx.x;
  int lane = tid & 63;
  int p = __builtin_amdgcn_readfirstlane(tid >> 6);  // k3 pair, 0..7
  const float4* xg = (const float4*)(x + (long)bn1 * 16384);
  const float* wrow = wtf + 4 * p;  // wave-uniform base -> s_load; row stride 32
  float2 acc[4][2];                 // [n2 sub i][k3 of pair]
#pragma unroll
  for (int i = 0; i < 4; i++) {
    acc[i][0] = make_float2(0.f, 0.f);
    acc[i][1] = make_float2(0.f, 0.f);
  }
  // ---- T-phase over four n3 quarters ----
  for (int Q = 0; Q < 4; Q++) {
    if (Q) __syncthreads();  // all reads of previous quarter done
#pragma unroll
    for (int e = 0; e < 2; e++) {
      int idx = tid + e * 512;        // 1024 float4: 256 n2 x 4 quads
      int n2 = idx >> 2, qq = idx & 3;
      float4 v = xg[n2 * 16 + 4 * Q + qq];
      int cs = n2 ^ (qq * 4);  // write-conflict-killing swizzle (row>>2 = qq)
      sX[4 * qq + 0][cs] = v.x; sX[4 * qq + 1][cs] = v.y;
      sX[4 * qq + 2][cs] = v.z; sX[4 * qq + 3][cs] = v.w;
    }
    __syncthreads();
#pragma unroll
    for (int n3l = 0; n3l < 16; n3l++) {
      float4 xv = *(const float4*)&sX[n3l][(4 * lane) ^ ((n3l >> 2) * 4)];
      float4 w = *(const float4*)(wrow + (16 * Q + n3l) * 32);  // s_load x4
      acc[0][0].x = fmaf(xv.x, w.x, acc[0][0].x); acc[0][0].y = fmaf(xv.x, w.y, acc[0][0].y);
      acc[0][1].x = fmaf(xv.x, w.z, acc[0][1].x); acc[0][1].y = fmaf(xv.x, w.w, acc[0][1].y);
      acc[1][0].x = fmaf(xv.y, w.x, acc[1][0].x); acc[1][0].y = fmaf(xv.y, w.y, acc[1][0].y);
      acc[1][1].x = fmaf(xv.y, w.z, acc[1][1].x); acc[1][1].y = fmaf(xv.y, w.w, acc[1][1].y);
      acc[2][0].x = fmaf(xv.z, w.x, acc[2][0].x); acc[2][0].y = fmaf(xv.z, w.y, acc[2][0].y);
      acc[2][1].x = fmaf(xv.z, w.z, acc[2][1].x); acc[2][1].y = fmaf(xv.z, w.w, acc[2][1].y);
      acc[3][0].x = fmaf(xv.w, w.x, acc[3][0].x); acc[3][0].y = fmaf(xv.w, w.y, acc[3][0].y);
      acc[3][1].x = fmaf(xv.w, w.z, acc[3][1].x); acc[3][1].y = fmaf(xv.w, w.w, acc[3][1].y);
    }
  }
  // write At fragment: rows 4*lane..+3, cols 4p..4p+3 (k3=2p re/im, 2p+1 re/im)
#pragma unroll
  for (int i = 0; i < 4; i++) {
    *(float4*)&sAt[4 * lane + i][4 * p] =
        make_float4(acc[i][0].x, acc[i][0].y, acc[i][1].x, acc[i][1].y);
  }
  // ---- Y twiddle registers (static-index tables; loads overlap barrier) ----
  int k2 = lane & 31, s = lane >> 5;
  float2 W16[16], W1s[8];
#pragma unroll
  for (int a = 0; a < 16; a++) W16[a] = t16[a * 32 + k2];
#pragma unroll
  for (int u = 0; u < 8; u++) W1s[u] = t1[(2 * u + s) * 32 + k2];
  __syncthreads();
  // ---- Y-phase (all register-array indices compile-time) ----
  {
    float2 a0 = make_float2(0.f, 0.f), a1 = make_float2(0.f, 0.f);
#pragma unroll
    for (int a = 0; a < 16; a++) {
      float2 wa = W16[a];
#pragma unroll
      for (int u = 0; u < 8; u++) {
        int n2 = 16 * a + 2 * u + s;
        float4 av = *(const float4*)&sAt[n2][4 * p];  // broadcast b128
        float2 wb = W1s[u];
        float wx = fmaf(wa.x, wb.x, -wa.y * wb.y);
        float wy = fmaf(wa.x, wb.y, wa.y * wb.x);
        a0.x = fmaf(av.x, wx, fmaf(-av.y, wy, a0.x));
        a0.y = fmaf(av.x, wy, fmaf(av.y, wx, a0.y));
        a1.x = fmaf(av.z, wx, fmaf(-av.w, wy, a1.x));
        a1.y = fmaf(av.z, wy, fmaf(av.w, wx, a1.y));
      }
    }
    a0.x += __shfl_xor(a0.x, 32); a0.y += __shfl_xor(a0.y, 32);
    a1.x += __shfl_xor(a1.x, 32); a1.y += __shfl_xor(a1.y, 32);
    if (s == 0) {
      *(float4*)&Bm[(long)bn1 * 512 + k2 * 16 + 2 * p] =
          make_float4(a0.x, a0.y, a1.x, a1.y);
    }
  }
}

// ---------------- Step C: X-axis forward DFT (all-LDS, Re-Im collapsed) ----------------
__global__ __launch_bounds__(512, 2) void k_fft_x(
    const float2* __restrict__ Bm, float* __restrict__ y,
    const float2* __restrict__ pqf,
    const float* __restrict__ w_tl, const float* __restrict__ w_tr,
    const float* __restrict__ w_bl, const float* __restrict__ w_br,
    const float* __restrict__ b_tl, const float* __restrict__ b_tr,
    const float* __restrict__ b_bl, const float* __restrict__ b_br) {
  __shared__ float2 sB[4096];   // [n1][k3] 32 KB
  __shared__ float2 sPQ[8192];  // full pqf table, 64 KB
  int b = blockIdx.x >> 5, k2 = blockIdx.x & 31;
  int tid = threadIdx.x;
  for (int i = tid; i < 4096; i += 512) {
    sB[i] = Bm[((long)(b * 256 + (i >> 4)) * 32 + k2) * 16 + (i & 15)];
  }
  const float4* pq4 = (const float4*)pqf;
  float4* sPQ4 = (float4*)sPQ;
#pragma unroll
  for (int e = 0; e < 8; e++) sPQ4[tid + e * 512] = pq4[tid + e * 512];
  __syncthreads();
  int k1 = tid >> 4, k3 = tid & 15;
  float acc = 0.f;
#pragma unroll 8
  for (int n1 = 0; n1 < 256; n1++) {
    float2 a = sB[n1 * 16 + k3];
    float2 w = sPQ[n1 * 32 + k1];  // (P, Qm)
    acc = fmaf(a.x, w.x, acc);
    acc = fmaf(a.y, w.y, acc);
  }
  const float* wsel = (k1 < 16) ? ((k2 < 16) ? w_tl : w_bl) : ((k2 < 16) ? w_tr : w_br);
  const float* bsel = (k1 < 16) ? ((k2 < 16) ? b_tl : b_bl) : ((k2 < 16) ? b_tr : b_br);
  int idx = ((k1 & 15) * 16 + (k2 & 15)) * 16 + k3;
  y[((b * 32 + k1) * 32 + k2) * 16 + k3] = fmaf(acc, wsel[idx], bsel[idx]);
}

// ---------------- Steps D+E fused: T-axis then Y-axis inverse DFT (GEMM form) ----------------
__global__ __launch_bounds__(256, 2) void k_inv_te(const float* __restrict__ y,
                                                   float2* __restrict__ E,
                                                   const float2* __restrict__ vt,
                                                   const float2* __restrict__ vxy) {
  __shared__ float sy[512];      // y[b,k1,:,:]  32x16
  __shared__ float2 svt[1024];   // vt[16][64]
  __shared__ float sD[32][132];  // D re/im interleaved: [k2][2*n3], pad
  __shared__ float sV[128][66];  // V c/s interleaved: [n2 local][2*k2], pad
  int blk = blockIdx.x;          // bk1*2 + h
  int h = blk & 1, bk1 = blk >> 1;
  int tid = threadIdx.x;
  ((float2*)sy)[tid] = ((const float2*)(y + (long)bk1 * 512))[tid];
#pragma unroll
  for (int e = 0; e < 4; e++) svt[tid + e * 256] = vt[tid + e * 256];
#pragma unroll
  for (int e = 0; e < 16; e++) {  // stage V panel: 128 rows x 32 k2
    int q = tid + e * 256;
    int n2l = q >> 5, k2 = q & 31;
    float2 v = vxy[(h * 128 + n2l) * 32 + k2];
    *(float2*)&sV[n2l][2 * k2] = v;
  }
  __syncthreads();
#pragma unroll
  for (int e = 0; e < 8; e++) {  // compute D (32x64 complex)
    int idx = tid + e * 256;
    int k2 = idx >> 6, n3i = idx & 63;
    float ax = 0.f, ay = 0.f;
#pragma unroll
    for (int k3 = 0; k3 < 16; k3++) {
      float yv = sy[k2 * 16 + k3];
      float2 v = svt[k3 * 64 + n3i];
      ax = fmaf(yv, v.x, ax); ay = fmaf(yv, v.y, ay);
    }
    *(float2*)&sD[k2][2 * n3i] = make_float2(ax, ay);
  }
  __syncthreads();
  int rg = tid >> 3, tn = tid & 7;  // rows n2l = rg*4+i; cols n3 = tn*8+j
  float acc[4][16];
#pragma unroll
  for (int i = 0; i < 4; i++)
#pragma unroll
    for (int j = 0; j < 16; j++) acc[i][j] = 0.f;
#pragma unroll 2
  for (int k2 = 0; k2 < 32; k2++) {
    float4 d0 = *(const float4*)&sD[k2][tn * 16];
    float4 d1 = *(const float4*)&sD[k2][tn * 16 + 4];
    float4 d2 = *(const float4*)&sD[k2][tn * 16 + 8];
    float4 d3 = *(const float4*)&sD[k2][tn * 16 + 12];
#pragma unroll
    for (int i = 0; i < 4; i++) {
      float2 v = *(const float2*)&sV[rg * 4 + i][2 * k2];
      float c = v.x, s = v.y;
      acc[i][0]  = fmaf(c, d0.x, fmaf(-s, d0.y, acc[i][0]));
      acc[i][1]  = fmaf(c, d0.y, fmaf( s, d0.x, acc[i][1]));
      acc[i][2]  = fmaf(c, d0.z, fmaf(-s, d0.w, acc[i][2]));
      acc[i][3]  = fmaf(c, d0.w, fmaf( s, d0.z, acc[i][3]));
      acc[i][4]  = fmaf(c, d1.x, fmaf(-s, d1.y, acc[i][4]));
      acc[i][5]  = fmaf(c, d1.y, fmaf( s, d1.x, acc[i][5]));
      acc[i][6]  = fmaf(c, d1.z, fmaf(-s, d1.w, acc[i][6]));
      acc[i][7]  = fmaf(c, d1.w, fmaf( s, d1.z, acc[i][7]));
      acc[i][8]  = fmaf(c, d2.x, fmaf(-s, d2.y, acc[i][8]));
      acc[i][9]  = fmaf(c, d2.y, fmaf( s, d2.x, acc[i][9]));
      acc[i][10] = fmaf(c, d2.z, fmaf(-s, d2.w, acc[i][10]));
      acc[i][11] = fmaf(c, d2.w, fmaf( s, d2.z, acc[i][11]));
      acc[i][12] = fmaf(c, d3.x, fmaf(-s, d3.y, acc[i][12]));
      acc[i][13] = fmaf(c, d3.y, fmaf( s, d3.x, acc[i][13]));
      acc[i][14] = fmaf(c, d3.z, fmaf(-s, d3.w, acc[i][14]));
      acc[i][15] = fmaf(c, d3.w, fmaf( s, d3.z, acc[i][15]));
    }
  }
#pragma unroll
  for (int i = 0; i < 4; i++) {
    int n2g = h * 128 + rg * 4 + i;
    float4* dst = (float4*)&E[((long)bk1 * 256 + n2g) * 64 + tn * 8];
    dst[0] = make_float4(acc[i][0], acc[i][1], acc[i][2], acc[i][3]);
    dst[1] = make_float4(acc[i][4], acc[i][5], acc[i][6], acc[i][7]);
    dst[2] = make_float4(acc[i][8], acc[i][9], acc[i][10], acc[i][11]);
    dst[3] = make_float4(acc[i][12], acc[i][13], acc[i][14], acc[i][15]);
  }
}

// ---------------- Step F: X-axis inverse DFT as full-column GEMM ----------------
__global__ __launch_bounds__(256, 2) void k_ifft_x(const float2* __restrict__ E,
                                                   float* __restrict__ out,
                                                   const float2* __restrict__ pqi) {
  __shared__ float sW[64][256];  // [kk][n1] 64 KB
  __shared__ float sD[64][64];   // [kk][col] 16 KB
  int blk = blockIdx.x;          // b*256 + tc
  int tc = blk & 255, b = blk >> 8;
  int tid = threadIdx.x;
  {
    const float4* pq4 = (const float4*)pqi;
#pragma unroll
    for (int r = 0; r < 16; r++) {
      float4 v = pq4[tid * 16 + r];
      sW[4 * r][tid] = v.x; sW[4 * r + 1][tid] = v.y;
      sW[4 * r + 2][tid] = v.z; sW[4 * r + 3][tid] = v.w;
    }
  }
  {
    const float4* Eg = (const float4*)E;
#pragma unroll
    for (int e = 0; e < 2; e++) {
      int tq = tid + e * 256;
      int k1 = tq >> 4, cq = tq & 15;
      const float4* src = Eg + ((long)(b * 32 + k1) * 8192) + tc * 32 + 2 * cq;
      float4 v0 = src[0], v1 = src[1];
      *(float4*)&sD[2 * k1][4 * cq]     = make_float4(v0.x, v0.z, v1.x, v1.z);
      *(float4*)&sD[2 * k1 + 1][4 * cq] = make_float4(v0.y, v0.w, v1.y, v1.w);
    }
  }
  __syncthreads();
  int tm = tid >> 3, tn = tid & 7;
  float acc[8][8];
#pragma unroll
  for (int i = 0; i < 8; i++)
#pragma unroll
    for (int j = 0; j < 8; j++) acc[i][j] = 0.f;
#pragma unroll 2
  for (int kk = 0; kk < 64; kk++) {
    float4 wa = *(const float4*)&sW[kk][tm * 8];
    float4 wb = *(const float4*)&sW[kk][tm * 8 + 4];
    float4 da = *(const float4*)&sD[kk][tn * 8];
    float4 db = *(const float4*)&sD[kk][tn * 8 + 4];
    float w[8] = {wa.x, wa.y, wa.z, wa.w, wb.x, wb.y, wb.z, wb.w};
    float d[8] = {da.x, da.y, da.z, da.w, db.x, db.y, db.z, db.w};
#pragma unroll
    for (int i = 0; i < 8; i++)
#pragma unroll
      for (int j = 0; j < 8; j++) acc[i][j] = fmaf(w[i], d[j], acc[i][j]);
  }
  float* ob = out + (long)b * 4194304 + (long)(tm * 8) * 16384 + tc * 64 + tn * 8;
#pragma unroll
  for (int i = 0; i < 8; i++) {
    float4* o = (float4*)(ob + (long)i * 16384);
    o[0] = make_float4(acc[i][0], acc[i][1], acc[i][2], acc[i][3]);
    o[1] = make_float4(acc[i][4], acc[i][5], acc[i][6], acc[i][7]);
  }
}

extern "C" void kernel_launch(void* const* d_in, const int* in_sizes, int n_in,
                              void* d_out, int out_size, void* d_ws, size_t ws_size,
                              hipStream_t stream) {
  const float* x    = (const float*)d_in[0];
  const float* w_tl = (const float*)d_in[1];
  const float* w_tr = (const float*)d_in[2];
  const float* w_bl = (const float*)d_in[3];
  const float* w_br = (const float*)d_in[4];
  const float* b_tl = (const float*)d_in[5];
  const float* b_tr = (const float*)d_in[6];
  const float* b_bl = (const float*)d_in[7];
  const float* b_br = (const float*)d_in[8];
  float* out = (float*)d_out;
  char* ws = (char*)d_ws;

  // Workspace layout (bytes):
  float2* Bm  = (float2*)(ws + 0);          //  8,388,608  (8,256,32,16) c64
  float*  y   = (float*)(ws + 8388608);     //  2,097,152  (8,32,32,16)  f32
  float2* E   = (float2*)(ws + 10485760);   // 33,554,432  (8,32,256,64) c64
  float2* WT  = (float2*)(ws + 44040192);   //  8 KB
  float2* VT  = (float2*)(ws + 44048384);   //  8 KB
  float2* VXY = (float2*)(ws + 44056576);   // 64 KB
  float2* PQF = (float2*)(ws + 44122112);   // 64 KB
  float2* PQI = (float2*)(ws + 44187648);   // 64 KB
  float2* T16 = (float2*)(ws + 44253184);   //  4 KB
  float2* T1  = (float2*)(ws + 44257280);   //  4 KB  (end ~44.3 MB)

  k_tables<<<32, 256, 0, stream>>>(WT, VT, VXY, PQF, PQI, T16, T1);
  k_fwd<<<2048, 512, 0, stream>>>(x, Bm, (const float*)WT, T16, T1);
  k_fft_x<<<256, 512, 0, stream>>>(Bm, y, PQF, w_tl, w_tr, w_bl, w_br,
                                   b_tl, b_tr, b_bl, b_br);
  k_inv_te<<<512, 256, 0, stream>>>(y, E, VT, VXY);
  k_ifft_x<<<2048, 256, 0, stream>>>(E, out, PQI);
}

// Round 12
// 178.875 us; speedup vs baseline: 1.0596x; 1.0420x over previous
//
#include <hip/hip_runtime.h>

#define PI_D 3.141592653589793238462643383279502884

// x (8,256,256,64) f32 -> out (8,256,256,64) f32.
// Forward padded FFT (272,272,80) pad=8; x_ft = Re(F)-Im(F) on 4 corner blocks.
// Inverse (256,256,64); out = Re(G)-Im(G).
// Re-Im collapse: Re-Im(sum a*w) = sum a.x*P + a.y*Qm, P=c-s, Qm=-(c+s).

// ---------------- twiddle tables (double-precision build) ----------------
__global__ void k_tables(float2* __restrict__ wt, float2* __restrict__ vt,
                         float2* __restrict__ vxy,
                         float2* __restrict__ pqf, float2* __restrict__ pqi,
                         float2* __restrict__ t16, float2* __restrict__ t1) {
  int t = blockIdx.x * blockDim.x + threadIdx.x;
  if (t < 64 * 16) {  // wt[n3][k3] = exp(-2pi i k3 (n3+8)/80)
    int n3 = t >> 4, k3 = t & 15;
    int ph = (k3 * (n3 + 8)) % 80;
    double a = -2.0 * PI_D * (double)ph / 80.0;
    wt[t] = make_float2((float)cos(a), (float)sin(a));
  }
  if (t < 256 * 32) {  // pqf[n][k]: P,Qm of exp(-2pi i kk (n+8)/272), kk = k<16?k:240+k
    int n = t >> 5, k = t & 31;
    int kk = (k < 16) ? k : (240 + k);
    int ph = (kk * (n + 8)) % 272;
    double a = -2.0 * PI_D * (double)ph / 272.0;
    double c = cos(a), s = sin(a);
    pqf[t] = make_float2((float)(c - s), (float)(-(c + s)));
  }
  if (t < 512) {  // Y-twiddle factor tables: w(n2,k2) = t16[n2>>4][k2]*t1[n2&15][k2]
    int a = t >> 5, k = t & 31;
    int kk = (k < 16) ? k : (240 + k);
    int ph16 = (kk * 16 * a) % 272;
    double a16 = -2.0 * PI_D * (double)ph16 / 272.0;
    t16[t] = make_float2((float)cos(a16), (float)sin(a16));
    int ph1 = (kk * (a + 8)) % 272;  // C0 = exp(-2pi i kk*8/272) folded in
    double a1 = -2.0 * PI_D * (double)ph1 / 272.0;
    t1[t] = make_float2((float)cos(a1), (float)sin(a1));
  }
  if (t < 16 * 64) {  // vt[k3][n3] = exp(+2pi i k3 n3 / 64)
    int k3 = t >> 6, n3 = t & 63;
    int ph = (k3 * n3) & 63;
    double a = 2.0 * PI_D * (double)ph / 64.0;
    vt[t] = make_float2((float)cos(a), (float)sin(a));
  }
  if (t < 256 * 32) {  // vxy[n][k] = exp(+2pi i k n / 256); pqi scaled by 1/N
    int n = t >> 5, k = t & 31;
    int ph = (k * n) & 255;
    double a = 2.0 * PI_D * (double)ph / 256.0;
    double c = cos(a), s = sin(a);
    vxy[t] = make_float2((float)c, (float)s);
    const double inv = 1.0 / 4194304.0;  // 1/(256*256*64)
    pqi[t] = make_float2((float)((c - s) * inv), (float)((-(c + s)) * inv));
  }
}

// ---------------- Fused forward T+Y DFT (v4: LDS-pipe-minimal) ----------------
// T-phase: wave = (n2-group-of-64, k3-half); lane = one n2. Per n3:
//   1 conflict-free ds_read_b32 + wave-uniform s_load twiddles + 16 FMA.
// sA2[p][n2][{re0,im0,re1,im1}]: lane-contiguous b128 writes (conflict-free).
// Y-phase: wave = k3-pair p; two-stage sum_a t16[a]*(sum_u At*t1) -> 1152 FMA.
__global__ __launch_bounds__(512, 4) void k_fwd(const float* __restrict__ x,
                                                float2* __restrict__ Bm,
                                                const float* __restrict__ wtf,
                                                const float2* __restrict__ t16,
                                                const float2* __restrict__ t1) {
  __shared__ float sX[16][260];     // [n3 local][n2 xor-swizzled], 16.6 KB
  __shared__ float sA2[8][256][4];  // [p][n2][re0,im0,re1,im1], 32 KB
  int bn1 = blockIdx.x;
  int tid = threadIdx.x;
  int lane = tid & 63;
  int wv = __builtin_amdgcn_readfirstlane(tid >> 6);
  int g = wv >> 1, h = wv & 1;  // n2-group (0..3), k3-half (0..1)
  int n2own = g * 64 + lane;
  const float4* xg = (const float4*)(x + (long)bn1 * 16384);
  float2 a8[8];  // 8 complex k3 accumulators for this lane's n2
#pragma unroll
  for (int q = 0; q < 8; q++) a8[q] = make_float2(0.f, 0.f);
  // ---- T-phase over four n3 quarters ----
  for (int Q = 0; Q < 4; Q++) {
    if (Q) __syncthreads();  // all reads of previous quarter done
#pragma unroll
    for (int e = 0; e < 2; e++) {
      int idx = tid + e * 512;  // 1024 float4: 256 n2 x 4 quads
      int n2 = idx >> 2, qq = idx & 3;
      float4 v = xg[n2 * 16 + 4 * Q + qq];
      int cs = n2 ^ (qq * 4);  // write-conflict-killing swizzle (row>>2 = qq)
      sX[4 * qq + 0][cs] = v.x; sX[4 * qq + 1][cs] = v.y;
      sX[4 * qq + 2][cs] = v.z; sX[4 * qq + 3][cs] = v.w;
    }
    __syncthreads();
#pragma unroll
    for (int n3l = 0; n3l < 16; n3l++) {
      float xv = sX[n3l][n2own ^ ((n3l >> 2) * 4)];  // b32, contiguous
      const float4* w4 = (const float4*)(wtf + (16 * Q + n3l) * 32 + h * 16);
      float4 wA = w4[0], wB = w4[1], wC = w4[2], wD = w4[3];  // s_load (uniform)
      a8[0].x = fmaf(xv, wA.x, a8[0].x); a8[0].y = fmaf(xv, wA.y, a8[0].y);
      a8[1].x = fmaf(xv, wA.z, a8[1].x); a8[1].y = fmaf(xv, wA.w, a8[1].y);
      a8[2].x = fmaf(xv, wB.x, a8[2].x); a8[2].y = fmaf(xv, wB.y, a8[2].y);
      a8[3].x = fmaf(xv, wB.z, a8[3].x); a8[3].y = fmaf(xv, wB.w, a8[3].y);
      a8[4].x = fmaf(xv, wC.x, a8[4].x); a8[4].y = fmaf(xv, wC.y, a8[4].y);
      a8[5].x = fmaf(xv, wC.z, a8[5].x); a8[5].y = fmaf(xv, wC.w, a8[5].y);
      a8[6].x = fmaf(xv, wD.x, a8[6].x); a8[6].y = fmaf(xv, wD.y, a8[6].y);
      a8[7].x = fmaf(xv, wD.z, a8[7].x); a8[7].y = fmaf(xv, wD.w, a8[7].y);
    }
  }
  // write sA2: this lane's n2, its 4 p-planes (k3 = 2p, 2p+1). Contiguous b128.
#pragma unroll
  for (int pp = 0; pp < 4; pp++) {
    int p = h * 4 + pp;
    *(float4*)&sA2[p][n2own][0] =
        make_float4(a8[2 * pp].x, a8[2 * pp].y, a8[2 * pp + 1].x, a8[2 * pp + 1].y);
  }
  // ---- Y twiddle registers (static-index tables; loads overlap barrier) ----
  int k2 = lane & 31, s = lane >> 5;
  float2 W16[16], W1s[8];
#pragma unroll
  for (int a = 0; a < 16; a++) W16[a] = t16[a * 32 + k2];
#pragma unroll
  for (int u = 0; u < 8; u++) W1s[u] = t1[(2 * u + s) * 32 + k2];
  __syncthreads();
  // ---- Y-phase: two-stage DFT (inner over u with t1, outer over a with t16) ----
  {
    int p = wv;  // k3 pair
    float2 A0 = make_float2(0.f, 0.f), A1 = make_float2(0.f, 0.f);
#pragma unroll
    for (int a = 0; a < 16; a++) {
      float2 S0 = make_float2(0.f, 0.f), S1 = make_float2(0.f, 0.f);
#pragma unroll
      for (int u = 0; u < 8; u++) {
        int n2 = 16 * a + 2 * u + s;
        float4 av = *(const float4*)&sA2[p][n2][0];  // 2-group broadcast b128
        float2 wb = W1s[u];
        S0.x = fmaf(av.x, wb.x, fmaf(-av.y, wb.y, S0.x));
        S0.y = fmaf(av.x, wb.y, fmaf(av.y, wb.x, S0.y));
        S1.x = fmaf(av.z, wb.x, fmaf(-av.w, wb.y, S1.x));
        S1.y = fmaf(av.z, wb.y, fmaf(av.w, wb.x, S1.y));
      }
      float2 wa = W16[a];
      A0.x = fmaf(S0.x, wa.x, fmaf(-S0.y, wa.y, A0.x));
      A0.y = fmaf(S0.x, wa.y, fmaf(S0.y, wa.x, A0.y));
      A1.x = fmaf(S1.x, wa.x, fmaf(-S1.y, wa.y, A1.x));
      A1.y = fmaf(S1.x, wa.y, fmaf(S1.y, wa.x, A1.y));
    }
    A0.x += __shfl_xor(A0.x, 32); A0.y += __shfl_xor(A0.y, 32);
    A1.x += __shfl_xor(A1.x, 32); A1.y += __shfl_xor(A1.y, 32);
    if (s == 0) {
      *(float4*)&Bm[(long)bn1 * 512 + k2 * 16 + 2 * p] =
          make_float4(A0.x, A0.y, A1.x, A1.y);
    }
  }
}

// ---------------- Step C: X-axis forward DFT (all-LDS, Re-Im collapsed) ----------------
__global__ __launch_bounds__(512, 2) void k_fft_x(
    const float2* __restrict__ Bm, float* __restrict__ y,
    const float2* __restrict__ pqf,
    const float* __restrict__ w_tl, const float* __restrict__ w_tr,
    const float* __restrict__ w_bl, const float* __restrict__ w_br,
    const float* __restrict__ b_tl, const float* __restrict__ b_tr,
    const float* __restrict__ b_bl, const float* __restrict__ b_br) {
  __shared__ float2 sB[4096];   // [n1][k3] 32 KB
  __shared__ float2 sPQ[8192];  // full pqf table, 64 KB
  int b = blockIdx.x >> 5, k2 = blockIdx.x & 31;
  int tid = threadIdx.x;
  for (int i = tid; i < 4096; i += 512) {
    sB[i] = Bm[((long)(b * 256 + (i >> 4)) * 32 + k2) * 16 + (i & 15)];
  }
  const float4* pq4 = (const float4*)pqf;
  float4* sPQ4 = (float4*)sPQ;
#pragma unroll
  for (int e = 0; e < 8; e++) sPQ4[tid + e * 512] = pq4[tid + e * 512];
  __syncthreads();
  int k1 = tid >> 4, k3 = tid & 15;
  float acc = 0.f;
#pragma unroll 8
  for (int n1 = 0; n1 < 256; n1++) {
    float2 a = sB[n1 * 16 + k3];
    float2 w = sPQ[n1 * 32 + k1];  // (P, Qm)
    acc = fmaf(a.x, w.x, acc);
    acc = fmaf(a.y, w.y, acc);
  }
  const float* wsel = (k1 < 16) ? ((k2 < 16) ? w_tl : w_bl) : ((k2 < 16) ? w_tr : w_br);
  const float* bsel = (k1 < 16) ? ((k2 < 16) ? b_tl : b_bl) : ((k2 < 16) ? b_tr : b_br);
  int idx = ((k1 & 15) * 16 + (k2 & 15)) * 16 + k3;
  y[((b * 32 + k1) * 32 + k2) * 16 + k3] = fmaf(acc, wsel[idx], bsel[idx]);
}

// ---------------- Steps D+E fused: T-axis then Y-axis inverse DFT (GEMM form) ----------------
__global__ __launch_bounds__(256, 2) void k_inv_te(const float* __restrict__ y,
                                                   float2* __restrict__ E,
                                                   const float2* __restrict__ vt,
                                                   const float2* __restrict__ vxy) {
  __shared__ float sy[512];      // y[b,k1,:,:]  32x16
  __shared__ float2 svt[1024];   // vt[16][64]
  __shared__ float sD[32][132];  // D re/im interleaved: [k2][2*n3], pad
  __shared__ float sV[128][66];  // V c/s interleaved: [n2 local][2*k2], pad
  int blk = blockIdx.x;          // bk1*2 + h
  int h = blk & 1, bk1 = blk >> 1;
  int tid = threadIdx.x;
  ((float2*)sy)[tid] = ((const float2*)(y + (long)bk1 * 512))[tid];
#pragma unroll
  for (int e = 0; e < 4; e++) svt[tid + e * 256] = vt[tid + e * 256];
#pragma unroll
  for (int e = 0; e < 16; e++) {  // stage V panel: 128 rows x 32 k2
    int q = tid + e * 256;
    int n2l = q >> 5, k2 = q & 31;
    float2 v = vxy[(h * 128 + n2l) * 32 + k2];
    *(float2*)&sV[n2l][2 * k2] = v;
  }
  __syncthreads();
#pragma unroll
  for (int e = 0; e < 8; e++) {  // compute D (32x64 complex)
    int idx = tid + e * 256;
    int k2 = idx >> 6, n3i = idx & 63;
    float ax = 0.f, ay = 0.f;
#pragma unroll
    for (int k3 = 0; k3 < 16; k3++) {
      float yv = sy[k2 * 16 + k3];
      float2 v = svt[k3 * 64 + n3i];
      ax = fmaf(yv, v.x, ax); ay = fmaf(yv, v.y, ay);
    }
    *(float2*)&sD[k2][2 * n3i] = make_float2(ax, ay);
  }
  __syncthreads();
  int rg = tid >> 3, tn = tid & 7;  // rows n2l = rg*4+i; cols n3 = tn*8+j
  float acc[4][16];
#pragma unroll
  for (int i = 0; i < 4; i++)
#pragma unroll
    for (int j = 0; j < 16; j++) acc[i][j] = 0.f;
#pragma unroll 2
  for (int k2 = 0; k2 < 32; k2++) {
    float4 d0 = *(const float4*)&sD[k2][tn * 16];
    float4 d1 = *(const float4*)&sD[k2][tn * 16 + 4];
    float4 d2 = *(const float4*)&sD[k2][tn * 16 + 8];
    float4 d3 = *(const float4*)&sD[k2][tn * 16 + 12];
#pragma unroll
    for (int i = 0; i < 4; i++) {
      float2 v = *(const float2*)&sV[rg * 4 + i][2 * k2];
      float c = v.x, s = v.y;
      acc[i][0]  = fmaf(c, d0.x, fmaf(-s, d0.y, acc[i][0]));
      acc[i][1]  = fmaf(c, d0.y, fmaf( s, d0.x, acc[i][1]));
      acc[i][2]  = fmaf(c, d0.z, fmaf(-s, d0.w, acc[i][2]));
      acc[i][3]  = fmaf(c, d0.w, fmaf( s, d0.z, acc[i][3]));
      acc[i][4]  = fmaf(c, d1.x, fmaf(-s, d1.y, acc[i][4]));
      acc[i][5]  = fmaf(c, d1.y, fmaf( s, d1.x, acc[i][5]));
      acc[i][6]  = fmaf(c, d1.z, fmaf(-s, d1.w, acc[i][6]));
      acc[i][7]  = fmaf(c, d1.w, fmaf( s, d1.z, acc[i][7]));
      acc[i][8]  = fmaf(c, d2.x, fmaf(-s, d2.y, acc[i][8]));
      acc[i][9]  = fmaf(c, d2.y, fmaf( s, d2.x, acc[i][9]));
      acc[i][10] = fmaf(c, d2.z, fmaf(-s, d2.w, acc[i][10]));
      acc[i][11] = fmaf(c, d2.w, fmaf( s, d2.z, acc[i][11]));
      acc[i][12] = fmaf(c, d3.x, fmaf(-s, d3.y, acc[i][12]));
      acc[i][13] = fmaf(c, d3.y, fmaf( s, d3.x, acc[i][13]));
      acc[i][14] = fmaf(c, d3.z, fmaf(-s, d3.w, acc[i][14]));
      acc[i][15] = fmaf(c, d3.w, fmaf( s, d3.z, acc[i][15]));
    }
  }
#pragma unroll
  for (int i = 0; i < 4; i++) {
    int n2g = h * 128 + rg * 4 + i;
    float4* dst = (float4*)&E[((long)bk1 * 256 + n2g) * 64 + tn * 8];
    dst[0] = make_float4(acc[i][0], acc[i][1], acc[i][2], acc[i][3]);
    dst[1] = make_float4(acc[i][4], acc[i][5], acc[i][6], acc[i][7]);
    dst[2] = make_float4(acc[i][8], acc[i][9], acc[i][10], acc[i][11]);
    dst[3] = make_float4(acc[i][12], acc[i][13], acc[i][14], acc[i][15]);
  }
}

// ---------------- Step F: X-axis inverse DFT as full-column GEMM ----------------
__global__ __launch_bounds__(256, 2) void k_ifft_x(const float2* __restrict__ E,
                                                   float* __restrict__ out,
                                                   const float2* __restrict__ pqi) {
  __shared__ float sW[64][256];  // [kk][n1] 64 KB
  __shared__ float sD[64][64];   // [kk][col] 16 KB
  int blk = blockIdx.x;          // b*256 + tc
  int tc = blk & 255, b = blk >> 8;
  int tid = threadIdx.x;
  {
    const float4* pq4 = (const float4*)pqi;
#pragma unroll
    for (int r = 0; r < 16; r++) {
      float4 v = pq4[tid * 16 + r];
      sW[4 * r][tid] = v.x; sW[4 * r + 1][tid] = v.y;
      sW[4 * r + 2][tid] = v.z; sW[4 * r + 3][tid] = v.w;
    }
  }
  {
    const float4* Eg = (const float4*)E;
#pragma unroll
    for (int e = 0; e < 2; e++) {
      int tq = tid + e * 256;
      int k1 = tq >> 4, cq = tq & 15;
      const float4* src = Eg + ((long)(b * 32 + k1) * 8192) + tc * 32 + 2 * cq;
      float4 v0 = src[0], v1 = src[1];
      *(float4*)&sD[2 * k1][4 * cq]     = make_float4(v0.x, v0.z, v1.x, v1.z);
      *(float4*)&sD[2 * k1 + 1][4 * cq] = make_float4(v0.y, v0.w, v1.y, v1.w);
    }
  }
  __syncthreads();
  int tm = tid >> 3, tn = tid & 7;
  float acc[8][8];
#pragma unroll
  for (int i = 0; i < 8; i++)
#pragma unroll
    for (int j = 0; j < 8; j++) acc[i][j] = 0.f;
#pragma unroll 2
  for (int kk = 0; kk < 64; kk++) {
    float4 wa = *(const float4*)&sW[kk][tm * 8];
    float4 wb = *(const float4*)&sW[kk][tm * 8 + 4];
    float4 da = *(const float4*)&sD[kk][tn * 8];
    float4 db = *(const float4*)&sD[kk][tn * 8 + 4];
    float w[8] = {wa.x, wa.y, wa.z, wa.w, wb.x, wb.y, wb.z, wb.w};
    float d[8] = {da.x, da.y, da.z, da.w, db.x, db.y, db.z, db.w};
#pragma unroll
    for (int i = 0; i < 8; i++)
#pragma unroll
      for (int j = 0; j < 8; j++) acc[i][j] = fmaf(w[i], d[j], acc[i][j]);
  }
  float* ob = out + (long)b * 4194304 + (long)(tm * 8) * 16384 + tc * 64 + tn * 8;
#pragma unroll
  for (int i = 0; i < 8; i++) {
    float4* o = (float4*)(ob + (long)i * 16384);
    o[0] = make_float4(acc[i][0], acc[i][1], acc[i][2], acc[i][3]);
    o[1] = make_float4(acc[i][4], acc[i][5], acc[i][6], acc[i][7]);
  }
}

extern "C" void kernel_launch(void* const* d_in, const int* in_sizes, int n_in,
                              void* d_out, int out_size, void* d_ws, size_t ws_size,
                              hipStream_t stream) {
  const float* x    = (const float*)d_in[0];
  const float* w_tl = (const float*)d_in[1];
  const float* w_tr = (const float*)d_in[2];
  const float* w_bl = (const float*)d_in[3];
  const float* w_br = (const float*)d_in[4];
  const float* b_tl = (const float*)d_in[5];
  const float* b_tr = (const float*)d_in[6];
  const float* b_bl = (const float*)d_in[7];
  const float* b_br = (const float*)d_in[8];
  float* out = (float*)d_out;
  char* ws = (char*)d_ws;

  // Workspace layout (bytes):
  float2* Bm  = (float2*)(ws + 0);          //  8,388,608  (8,256,32,16) c64
  float*  y   = (float*)(ws + 8388608);     //  2,097,152  (8,32,32,16)  f32
  float2* E   = (float2*)(ws + 10485760);   // 33,554,432  (8,32,256,64) c64
  float2* WT  = (float2*)(ws + 44040192);   //  8 KB
  float2* VT  = (float2*)(ws + 44048384);   //  8 KB
  float2* VXY = (float2*)(ws + 44056576);   // 64 KB
  float2* PQF = (float2*)(ws + 44122112);   // 64 KB
  float2* PQI = (float2*)(ws + 44187648);   // 64 KB
  float2* T16 = (float2*)(ws + 44253184);   //  4 KB
  float2* T1  = (float2*)(ws + 44257280);   //  4 KB  (end ~44.3 MB)

  k_tables<<<32, 256, 0, stream>>>(WT, VT, VXY, PQF, PQI, T16, T1);
  k_fwd<<<2048, 512, 0, stream>>>(x, Bm, (const float*)WT, T16, T1);
  k_fft_x<<<256, 512, 0, stream>>>(Bm, y, PQF, w_tl, w_tr, w_bl, w_br,
                                   b_tl, b_tr, b_bl, b_br);
  k_inv_te<<<512, 256, 0, stream>>>(y, E, VT, VXY);
  k_ifft_x<<<2048, 256, 0, stream>>>(E, out, PQI);
}